// Round 8
// baseline (312.608 us; speedup 1.0000x reference)
//
#include <hip/hip_runtime.h>
#include <hip/hip_cooperative_groups.h>
#include <stdint.h>

namespace cg = cooperative_groups;

#define BS 7
#define HM 50
#define WM 50
#define HH 56
#define WW 56
#define PLANE_IN  2500             // 50*50
#define PLANE_OUT 3136             // 56*56
#define NPLANES   16384            // 64*256
#define COUNT_M   51380224.0f      // 64*256*56*56 = 49*2^20, exact fp32
#define PPB       8                // planes per block
#define NBLOCKS   (NPLANES / PPB)  // 2048 = 8 blocks/CU x 256 CUs, co-resident

typedef unsigned long long u64;

// Single cooperative kernel. Phase 1: dilate 8 planes -> keep-bitmap in LDS
// (no global bitmap round-trip) + per-block count. grid.sync(). Phase 2:
// every block sums the 2048 counts (8KB) -> scale -> streams its 8 planes.
// R7 diagnostic showed both R2 kernels were overhead-bound (occ 79%, VALU 26%,
// HBM 61%), not BW-bound: thin blocks couldn't amortize prologues. Fat blocks
// + LDS-resident bitmap + one launch attacks exactly that.
__global__ __launch_bounds__(256, 8) void dropblock_fused(
    const float* __restrict__ x,
    const float* __restrict__ mask,
    unsigned* __restrict__ counts,
    float* __restrict__ out)
{
    __shared__ u64 rowbits[PPB * HM];   // 3.2 KB seed rows
    __shared__ u64 rowdil[PPB * HM];    // 3.2 KB row-dilated
    __shared__ u64 bits[PPB * HH];      // 3.5 KB keep bitmap (lives across sync)
    __shared__ unsigned wsum[4];
    __shared__ float s_scale;

    const int tid = threadIdx.x;
    const int b = blockIdx.x;

    // ---- Phase 1: dilation (R4's proven code, bitmap -> LDS) ----
    for (int i = tid; i < PPB * HM; i += 256) rowbits[i] = 0ULL;
    __syncthreads();

    // 8 contiguous planes = 5000 float4, coalesced; sparse seeds -> atomicOr.
    const float4* mp = reinterpret_cast<const float4*>(
        mask + (size_t)b * (PPB * PLANE_IN));
    for (int j = tid; j < PPB * PLANE_IN / 4; j += 256) {  // ~19.5 iters
        float4 v = mp[j];
        if (v.x == 0.f && v.y == 0.f && v.z == 0.f && v.w == 0.f) continue;
        const int e = 4 * j;
        const int plane = e / PLANE_IN;
        const int rem = e - plane * PLANE_IN;
        int r = rem / WM;
        int w = rem - r * WM;
        float vv[4] = {v.x, v.y, v.z, v.w};
#pragma unroll
        for (int k = 0; k < 4; ++k) {
            if (vv[k] != 0.f) atomicOr(&rowbits[plane * HM + r], 1ULL << w);
            if (++w == WM) { w = 0; ++r; }   // float4 may straddle a row
        }
    }
    __syncthreads();

    // Row dilation: bit w -> bits w..w+6.
    for (int i = tid; i < PPB * HM; i += 256) {
        u64 bb = rowbits[i];
        u64 s = bb | (bb << 1);  // shifts 0..1
        s |= s << 2;             // 0..3
        s |= s << 3;             // 0..6
        rowdil[i] = s;
    }
    __syncthreads();

    // Column dilation + invert + popcount; bitmap stays in LDS.
    unsigned pc = 0;
    for (int i = tid; i < PPB * HH; i += 256) {  // 448 words
        const int plane = i / HH;
        const int h = i - plane * HH;
        int lo = h - (BS - 1); if (lo < 0) lo = 0;
        int hi = h;            if (hi > HM - 1) hi = HM - 1;
        u64 d = 0ULL;
        for (int r = lo; r <= hi; ++r) d |= rowdil[plane * HM + r];
        u64 keep = ~d & ((1ULL << 56) - 1ULL);
        bits[i] = keep;
        pc += (unsigned)__popcll(keep);
    }
#pragma unroll
    for (int off = 32; off; off >>= 1) pc += __shfl_down(pc, off, 64);
    if ((tid & 63) == 0) wsum[tid >> 6] = pc;
    __syncthreads();
    if (tid == 0) {
        counts[b] = wsum[0] + wsum[1] + wsum[2] + wsum[3];
        __threadfence();  // device-scope: publish across XCD L2s before sync
    }

    cg::this_grid().sync();

    // ---- Phase 2: global count -> scale -> stream output ----
    const uint4* cp = reinterpret_cast<const uint4*>(counts);  // 512 uint4
    uint4 ca = cp[tid];
    uint4 cb = cp[tid + 256];
    unsigned s = ca.x + ca.y + ca.z + ca.w + cb.x + cb.y + cb.z + cb.w;
#pragma unroll
    for (int off = 32; off; off >>= 1) s += __shfl_down(s, off, 64);
    if ((tid & 63) == 0) wsum[tid >> 6] = s;
    __syncthreads();
    if (tid == 0)
        s_scale = COUNT_M / (float)(wsum[0] + wsum[1] + wsum[2] + wsum[3]);
    __syncthreads();

    const float scale = s_scale;
    // 8 contiguous planes = 6272 float4 per block; skip x load when the
    // 4-pixel nibble is all-dropped (~94% of words; FETCH stays ~25 MB).
    const size_t fbase = (size_t)b * (PPB * PLANE_OUT / 4);
    const float4* xp = reinterpret_cast<const float4*>(x) + fbase;
    float4* op = reinterpret_cast<float4*>(out) + fbase;

    for (int j = tid; j < PPB * PLANE_OUT / 4; j += 256) {  // ~24.5 iters
        const int wword = j / 14;              // 14 float4 per 56-pixel row
        const int q = j - 14 * wword;
        const unsigned m4 = (unsigned)((bits[wword] >> (4 * q)) & 0xFULL);
        float4 o = {0.f, 0.f, 0.f, 0.f};
        if (m4) {
            float4 v = xp[j];
            o.x = (m4 & 1u) ? v.x * scale : 0.f;
            o.y = (m4 & 2u) ? v.y * scale : 0.f;
            o.z = (m4 & 4u) ? v.z * scale : 0.f;
            o.w = (m4 & 8u) ? v.w * scale : 0.f;
        }
        op[j] = o;
    }
}

extern "C" void kernel_launch(void* const* d_in, const int* in_sizes, int n_in,
                              void* d_out, int out_size, void* d_ws, size_t ws_size,
                              hipStream_t stream)
{
    const float* x    = (const float*)d_in[0];   // (64,256,56,56) f32
    const float* mask = (const float*)d_in[1];   // (64,256,50,50) f32
    float* out = (float*)d_out;
    unsigned* counts = (unsigned*)d_ws;          // 2048 u32, all written pre-sync

    void* args[] = {(void*)&x, (void*)&mask, (void*)&counts, (void*)&out};
    hipLaunchCooperativeKernel((const void*)dropblock_fused,
                               dim3(NBLOCKS), dim3(256), args, 0, stream);
}

// Round 9
// 221.446 us; speedup vs baseline: 1.4117x; 1.4117x over previous
//
#include <hip/hip_runtime.h>
#include <stdint.h>

#define BS 7
#define HM 50
#define WM 50
#define HH 56
#define WW 56
#define PLANE_IN  (HM * WM)   // 2500
#define PLANE_OUT (HH * WW)   // 3136
#define NPLANES   (64 * 256)  // 16384
#define COUNT_M   51380224.0f // 64*256*56*56 = 49 * 2^20, exact in fp32
#define K1_REPS   5           // DIAGNOSTIC: x5 internal repeat so the K1
                              // dispatch displaces the 117us harness fills
                              // from rocprof's top-5 -> first-ever K1 counters.

typedef unsigned long long u64;

// ===== R2 configuration verbatim (110 us) except K1's rep loop =====

// Kernel 1: per-plane 7x7 dilation, 16384 blocks, LDS atomicOr seeds,
// per-plane count via plain store (no global atomics). Repeated x5 for
// measurement; each rep re-zeros LDS and recomputes identical results.
__global__ __launch_bounds__(256) void dropblock_dilate(
    const float* __restrict__ mask,
    u64* __restrict__ bitmap,
    unsigned* __restrict__ counts)
{
    __shared__ u64 rowbits[HM];
    __shared__ u64 rowdil[HM];
    __shared__ unsigned cnt;

    const int tid = threadIdx.x;
    const int p = blockIdx.x;

    for (int rep = 0; rep < K1_REPS; ++rep) {
        if (tid < HM) rowbits[tid] = 0ULL;
        if (tid == 0) cnt = 0;
        __syncthreads();

        const float4* mp = reinterpret_cast<const float4*>(mask + (size_t)p * PLANE_IN);
        for (int j = tid; j < PLANE_IN / 4; j += 256) {  // 625 float4, no tail
            float4 v = mp[j];
            const int e = 4 * j;
            float vv[4] = {v.x, v.y, v.z, v.w};
#pragma unroll
            for (int k = 0; k < 4; ++k) {
                if (vv[k] != 0.0f) {
                    int idx = e + k;
                    int r = idx / WM;
                    int w = idx - r * WM;
                    atomicOr(&rowbits[r], 1ULL << w);
                }
            }
        }
        __syncthreads();

        if (tid < HM) {
            u64 b = rowbits[tid];
            u64 s = b | (b << 1);  // shifts 0..1
            s |= s << 2;           // 0..3
            s |= s << 3;           // 0..6
            rowdil[tid] = s;
        }
        __syncthreads();

        unsigned pc = 0;
        if (tid < HH) {
            const int h = tid;
            int lo = h - (BS - 1); if (lo < 0) lo = 0;
            int hi = h;            if (hi > HM - 1) hi = HM - 1;
            u64 d = 0ULL;
            for (int r = lo; r <= hi; ++r) d |= rowdil[r];
            u64 keep = ~d & ((1ULL << 56) - 1ULL);
            bitmap[(size_t)p * HH + h] = keep;
            pc = (unsigned)__popcll(keep);
        }
        if (pc) atomicAdd(&cnt, pc);  // LDS atomic only
        __syncthreads();
        if (tid == 0) counts[p] = cnt;
        __syncthreads();  // protect LDS re-zero next rep
    }
}

// Kernel 1.5: one block sums the 16384 per-plane counts -> scale factor.
__global__ __launch_bounds__(1024) void dropblock_reduce(
    const unsigned* __restrict__ counts,
    float* __restrict__ scale)
{
    __shared__ unsigned wsum[16];
    unsigned s = 0;
    for (int i = threadIdx.x; i < NPLANES; i += 1024) s += counts[i];
#pragma unroll
    for (int off = 32; off > 0; off >>= 1) s += __shfl_down(s, off, 64);
    const int wave = threadIdx.x >> 6;
    const int lane = threadIdx.x & 63;
    if (lane == 0) wsum[wave] = s;
    __syncthreads();
    if (threadIdx.x == 0) {
        unsigned tot = 0;
#pragma unroll
        for (int w = 0; w < 16; ++w) tot += wsum[w];
        *scale = COUNT_M / (float)tot;
    }
}

// Kernel 2: R2 verbatim (59 us cold / 44 warm, measured R7).
__global__ __launch_bounds__(256) void dropblock_scale(
    const float* __restrict__ x,
    const u64* __restrict__ bitmap,
    const float* __restrict__ scaleptr,
    float* __restrict__ out)
{
    __shared__ u64 bitsLDS[HH];
    __shared__ float s_scale;

    const int tid = threadIdx.x;
    const int p = blockIdx.x;

    if (tid < HH) bitsLDS[tid] = bitmap[(size_t)p * HH + tid];
    if (tid == 0) s_scale = *scaleptr;
    __syncthreads();

    const float scale = s_scale;
    const float4* xp = reinterpret_cast<const float4*>(x + (size_t)p * PLANE_OUT);
    float4* op = reinterpret_cast<float4*>(out + (size_t)p * PLANE_OUT);

    for (int j = tid; j < PLANE_OUT / 4; j += 256) {  // 784 float4
        const int h = j / (WW / 4);        // 14 float4 per row
        const int q = j - h * (WW / 4);
        const int w = 4 * q;
        const unsigned m4 = (unsigned)((bitsLDS[h] >> w) & 0xFULL);
        float4 o = {0.f, 0.f, 0.f, 0.f};
        if (m4) {
            float4 v = xp[j];
            o.x = (m4 & 1u) ? v.x * scale : 0.f;
            o.y = (m4 & 2u) ? v.y * scale : 0.f;
            o.z = (m4 & 4u) ? v.z * scale : 0.f;
            o.w = (m4 & 8u) ? v.w * scale : 0.f;
        }
        op[j] = o;
    }
}

extern "C" void kernel_launch(void* const* d_in, const int* in_sizes, int n_in,
                              void* d_out, int out_size, void* d_ws, size_t ws_size,
                              hipStream_t stream)
{
    const float* x    = (const float*)d_in[0];   // (64,256,56,56) f32
    const float* mask = (const float*)d_in[1];   // (64,256,50,50) f32
    float* out = (float*)d_out;

    // d_ws layout (as R2):
    //   [0, 64KB)      counts[16384] (u32)
    //   [64KB, 64KB+4) scale (f32)
    //   [65KB, ..)     bitmap: 16384*56 u64 = 7.34 MB
    unsigned* counts = (unsigned*)d_ws;
    float* scale = (float*)((char*)d_ws + 65536);
    u64* bitmap = (u64*)((char*)d_ws + 66560);

    dropblock_dilate<<<NPLANES, 256, 0, stream>>>(mask, bitmap, counts);
    dropblock_reduce<<<1, 1024, 0, stream>>>(counts, scale);
    dropblock_scale<<<NPLANES, 256, 0, stream>>>(x, bitmap, scale, out);
}

// Round 10
// 110.995 us; speedup vs baseline: 2.8164x; 1.9951x over previous
//
#include <hip/hip_runtime.h>
#include <stdint.h>

#define BS 7
#define HM 50
#define WM 50
#define HH 56
#define WW 56
#define PLANE_IN  (HM * WM)   // 2500
#define PLANE_OUT (HH * WW)   // 3136
#define NPLANES   (64 * 256)  // 16384
#define COUNT_M   51380224.0f // 64*256*56*56 = 49 * 2^20, exact in fp32

typedef unsigned long long u64;

// Kernel 1: R2 verbatim (measured R9: ~28us warm / ~44us cold; latency-bound,
// not DS-atomic-bound -- conflicts only ~76 cy/block).
__global__ __launch_bounds__(256) void dropblock_dilate(
    const float* __restrict__ mask,
    u64* __restrict__ bitmap,
    unsigned* __restrict__ counts)
{
    __shared__ u64 rowbits[HM];
    __shared__ u64 rowdil[HM];
    __shared__ unsigned cnt;

    const int tid = threadIdx.x;
    const int p = blockIdx.x;

    if (tid < HM) rowbits[tid] = 0ULL;
    if (tid == 0) cnt = 0;
    __syncthreads();

    const float4* mp = reinterpret_cast<const float4*>(mask + (size_t)p * PLANE_IN);
    for (int j = tid; j < PLANE_IN / 4; j += 256) {  // 625 float4, no tail
        float4 v = mp[j];
        const int e = 4 * j;
        float vv[4] = {v.x, v.y, v.z, v.w};
#pragma unroll
        for (int k = 0; k < 4; ++k) {
            if (vv[k] != 0.0f) {
                int idx = e + k;
                int r = idx / WM;
                int w = idx - r * WM;
                atomicOr(&rowbits[r], 1ULL << w);
            }
        }
    }
    __syncthreads();

    if (tid < HM) {
        u64 b = rowbits[tid];
        u64 s = b | (b << 1);  // shifts 0..1
        s |= s << 2;           // 0..3
        s |= s << 3;           // 0..6
        rowdil[tid] = s;
    }
    __syncthreads();

    unsigned pc = 0;
    if (tid < HH) {
        const int h = tid;
        int lo = h - (BS - 1); if (lo < 0) lo = 0;
        int hi = h;            if (hi > HM - 1) hi = HM - 1;
        u64 d = 0ULL;
        for (int r = lo; r <= hi; ++r) d |= rowdil[r];
        u64 keep = ~d & ((1ULL << 56) - 1ULL);
        bitmap[(size_t)p * HH + h] = keep;
        pc = (unsigned)__popcll(keep);
    }
    if (pc) atomicAdd(&cnt, pc);  // LDS atomic only
    __syncthreads();
    if (tid == 0) counts[p] = cnt;
}

// Kernel 1.5: one block sums the 16384 per-plane counts -> scale factor.
__global__ __launch_bounds__(1024) void dropblock_reduce(
    const unsigned* __restrict__ counts,
    float* __restrict__ scale)
{
    __shared__ unsigned wsum[16];
    unsigned s = 0;
    for (int i = threadIdx.x; i < NPLANES; i += 1024) s += counts[i];
#pragma unroll
    for (int off = 32; off > 0; off >>= 1) s += __shfl_down(s, off, 64);
    const int wave = threadIdx.x >> 6;
    const int lane = threadIdx.x & 63;
    if (lane == 0) wsum[wave] = s;
    __syncthreads();
    if (threadIdx.x == 0) {
        unsigned tot = 0;
#pragma unroll
        for (int w = 0; w < 16; ++w) tot += wsum[w];
        *scale = COUNT_M / (float)tot;
    }
}

// Kernel 2 (grid-stride rewrite): no LDS, no barriers, no per-block prologue.
// Thread owns float4-word j; bitmap word = bitmap[j/14] (u64 shared by 14
// consecutive lanes -> ~5 u64 = one cache line per wave). 24.5 iters/thread
// amortizes startup (R2's K2 had 3 iters behind an LDS prologue + barrier ->
// 59us at only 61% HBM / 26% VALU / 79% occ).
__global__ __launch_bounds__(256) void dropblock_scale(
    const float* __restrict__ x,
    const u64* __restrict__ bitmap,
    const float* __restrict__ scaleptr,
    float* __restrict__ out)
{
    const float scale = *scaleptr;  // uniform scalar load
    const float4* xp = reinterpret_cast<const float4*>(x);
    float4* op = reinterpret_cast<float4*>(out);

    const int total = NPLANES * (PLANE_OUT / 4);  // 12,845,056 float4 words
    const int stride = 2048 * 256;

    for (int j = (int)(blockIdx.x * 256 + threadIdx.x); j < total; j += stride) {
        const int row = j / 14;               // global row id == bitmap index
        const int q = j - row * 14;
        const unsigned m4 = (unsigned)((bitmap[row] >> (4 * q)) & 0xFULL);
        float4 o = {0.f, 0.f, 0.f, 0.f};
        if (m4) {
            float4 v = xp[j];
            o.x = (m4 & 1u) ? v.x * scale : 0.f;
            o.y = (m4 & 2u) ? v.y * scale : 0.f;
            o.z = (m4 & 4u) ? v.z * scale : 0.f;
            o.w = (m4 & 8u) ? v.w * scale : 0.f;
        }
        op[j] = o;
    }
}

extern "C" void kernel_launch(void* const* d_in, const int* in_sizes, int n_in,
                              void* d_out, int out_size, void* d_ws, size_t ws_size,
                              hipStream_t stream)
{
    const float* x    = (const float*)d_in[0];   // (64,256,56,56) f32
    const float* mask = (const float*)d_in[1];   // (64,256,50,50) f32
    float* out = (float*)d_out;

    // d_ws layout (as R2):
    //   [0, 64KB)      counts[16384] (u32)
    //   [64KB, 64KB+4) scale (f32)
    //   [65KB, ..)     bitmap: 16384*56 u64 = 7.34 MB
    unsigned* counts = (unsigned*)d_ws;
    float* scale = (float*)((char*)d_ws + 65536);
    u64* bitmap = (u64*)((char*)d_ws + 66560);

    dropblock_dilate<<<NPLANES, 256, 0, stream>>>(mask, bitmap, counts);
    dropblock_reduce<<<1, 1024, 0, stream>>>(counts, scale);
    dropblock_scale<<<2048, 256, 0, stream>>>(x, bitmap, scale, out);
}